// Round 2
// baseline (926.954 us; speedup 1.0000x reference)
//
#include <hip/hip_runtime.h>
#include <hip/hip_bf16.h>

static __device__ inline unsigned short f2bf(float f) {
    unsigned u = __float_as_uint(f);
    unsigned r = (u + 0x7fffu + ((u >> 16) & 1u)) >> 16;
    return (unsigned short)r;
}

// ---------------- Fused layer1+layer2: h2 = silu(LN(silu(LN(xe@W1+b1))@W2+b2)) ----------
__global__ __launch_bounds__(256) void mlp12_kernel(
    const float* __restrict__ xe,
    const float* __restrict__ W1, const float* __restrict__ b1,
    const float* __restrict__ g1, const float* __restrict__ be1,
    const float* __restrict__ W2, const float* __restrict__ b2,
    const float* __restrict__ g2, const float* __restrict__ be2,
    float* __restrict__ h2out, int E)
{
    __shared__ float As[64 * 132];
    __shared__ float Bs[16 * 128];
    __shared__ float redS[64 * 16];
    __shared__ float redQ[64 * 16];
    __shared__ float mrow[64];
    __shared__ float rrow[64];

    int t  = threadIdx.x;
    int tx = t & 15;        // output-col group (8 cols each)
    int ty = t >> 4;        // row group (4 rows each)
    int e0 = blockIdx.x * 64;

    // load A tile (64 x 128)
    for (int idx = t; idx < 64 * 32; idx += 256) {
        int row = idx >> 5;
        int c4  = (idx & 31) * 4;
        float4 v = make_float4(0.f, 0.f, 0.f, 0.f);
        if (e0 + row < E) v = *(const float4*)(xe + (size_t)(e0 + row) * 128 + c4);
        *(float4*)&As[row * 132 + c4] = v;
    }

    const float* Wl = W1; const float* bl = b1; const float* gl = g1; const float* bel = be1;
    float acc[4][8];

    for (int layer = 0; layer < 2; layer++) {
        for (int r = 0; r < 4; r++)
            for (int i = 0; i < 8; i++) acc[r][i] = 0.f;

        for (int kk = 0; kk < 128; kk += 16) {
            __syncthreads();
            for (int idx = t; idx < 16 * 32; idx += 256) {
                int row = idx >> 5;
                int c4  = (idx & 31) * 4;
                *(float4*)&Bs[row * 128 + c4] = *(const float4*)(Wl + (size_t)(kk + row) * 128 + c4);
            }
            __syncthreads();
            for (int k = 0; k < 16; k++) {
                float4 bv0 = *(float4*)&Bs[k * 128 + tx * 8];
                float4 bv1 = *(float4*)&Bs[k * 128 + tx * 8 + 4];
                float b[8] = {bv0.x, bv0.y, bv0.z, bv0.w, bv1.x, bv1.y, bv1.z, bv1.w};
                for (int r = 0; r < 4; r++) {
                    float a = As[(ty * 4 + r) * 132 + kk + k];
                    for (int i = 0; i < 8; i++) acc[r][i] += a * b[i];
                }
            }
        }

        // bias, then LayerNorm stats across the 128 cols of each row
        float gg[8], bebe[8];
        for (int i = 0; i < 8; i++) {
            float bb = bl[tx * 8 + i];
            gg[i]    = gl[tx * 8 + i];
            bebe[i]  = bel[tx * 8 + i];
            for (int r = 0; r < 4; r++) acc[r][i] += bb;
        }
        for (int r = 0; r < 4; r++) {
            float s = 0.f, q = 0.f;
            for (int i = 0; i < 8; i++) { s += acc[r][i]; q += acc[r][i] * acc[r][i]; }
            redS[(ty * 4 + r) * 16 + tx] = s;
            redQ[(ty * 4 + r) * 16 + tx] = q;
        }
        __syncthreads();
        if (t < 64) {
            float s = 0.f, q = 0.f;
            for (int i = 0; i < 16; i++) { s += redS[t * 16 + i]; q += redQ[t * 16 + i]; }
            float mu  = s * (1.f / 128.f);
            float var = q * (1.f / 128.f) - mu * mu;
            mrow[t] = mu;
            rrow[t] = rsqrtf(var + 1e-6f);
        }
        __syncthreads();
        for (int r = 0; r < 4; r++) {
            int e_loc = ty * 4 + r;
            float mu = mrow[e_loc], rs = rrow[e_loc];
            for (int i = 0; i < 8; i++) {
                float v = (acc[r][i] - mu) * rs * gg[i] + bebe[i];
                acc[r][i] = v / (1.f + __expf(-v));   // silu
            }
        }
        if (layer == 0) {
            // write h1 back into As as input of layer 2
            for (int r = 0; r < 4; r++) {
                int e_loc = ty * 4 + r;
                for (int i = 0; i < 8; i++) As[e_loc * 132 + tx * 8 + i] = acc[r][i];
            }
            __syncthreads();
            Wl = W2; bl = b2; gl = g2; bel = be2;
        } else {
            for (int r = 0; r < 4; r++) {
                int e = e0 + ty * 4 + r;
                if (e < E) {
                    *(float4*)(h2out + (size_t)e * 128 + tx * 8)     = make_float4(acc[r][0], acc[r][1], acc[r][2], acc[r][3]);
                    *(float4*)(h2out + (size_t)e * 128 + tx * 8 + 4) = make_float4(acc[r][4], acc[r][5], acc[r][6], acc[r][7]);
                }
            }
        }
    }
}

// ---------------- Layer 3: h3 = h2 @ W3 + b3, stored bf16 [E,640] -------------------
__global__ __launch_bounds__(256) void gemm3_kernel(
    const float* __restrict__ h2, const float* __restrict__ W3,
    const float* __restrict__ b3, unsigned short* __restrict__ h3b, int E)
{
    __shared__ float As[64 * 132];
    __shared__ float Bs[16 * 128];
    int t  = threadIdx.x;
    int tx = t & 15;
    int ty = t >> 4;
    int e0 = blockIdx.x * 64;
    int n0 = blockIdx.y * 128;

    for (int idx = t; idx < 64 * 32; idx += 256) {
        int row = idx >> 5;
        int c4  = (idx & 31) * 4;
        float4 v = make_float4(0.f, 0.f, 0.f, 0.f);
        if (e0 + row < E) v = *(const float4*)(h2 + (size_t)(e0 + row) * 128 + c4);
        *(float4*)&As[row * 132 + c4] = v;
    }

    float acc[4][8];
    for (int r = 0; r < 4; r++)
        for (int i = 0; i < 8; i++) acc[r][i] = 0.f;

    for (int kk = 0; kk < 128; kk += 16) {
        __syncthreads();
        for (int idx = t; idx < 16 * 32; idx += 256) {
            int row = idx >> 5;
            int c4  = (idx & 31) * 4;
            *(float4*)&Bs[row * 128 + c4] = *(const float4*)(W3 + (size_t)(kk + row) * 640 + n0 + c4);
        }
        __syncthreads();
        for (int k = 0; k < 16; k++) {
            float4 bv0 = *(float4*)&Bs[k * 128 + tx * 8];
            float4 bv1 = *(float4*)&Bs[k * 128 + tx * 8 + 4];
            float b[8] = {bv0.x, bv0.y, bv0.z, bv0.w, bv1.x, bv1.y, bv1.z, bv1.w};
            for (int r = 0; r < 4; r++) {
                float a = As[(ty * 4 + r) * 132 + kk + k];
                for (int i = 0; i < 8; i++) acc[r][i] += a * b[i];
            }
        }
    }

    for (int r = 0; r < 4; r++) {
        int e = e0 + ty * 4 + r;
        if (e < E) {
            unsigned p[4];
            for (int i = 0; i < 4; i++) {
                float v0 = acc[r][2 * i]     + b3[n0 + tx * 8 + 2 * i];
                float v1 = acc[r][2 * i + 1] + b3[n0 + tx * 8 + 2 * i + 1];
                p[i] = (unsigned)f2bf(v0) | ((unsigned)f2bf(v1) << 16);
            }
            *(uint4*)(h3b + (size_t)e * 640 + n0 + tx * 8) = make_uint4(p[0], p[1], p[2], p[3]);
        }
    }
}

// ---------------- CSR build ---------------------------------------------------------
__global__ void hist_kernel(const int* __restrict__ ei, const int* __restrict__ noff,
                            int* __restrict__ counts, int E)
{
    int i = blockIdx.x * blockDim.x + threadIdx.x;
    if (i < E) {
        int tgt = ei[E + i] - noff[0];
        atomicAdd(&counts[tgt], 1);
    }
}

__global__ __launch_bounds__(1024) void scan_kernel(const int* __restrict__ counts,
                                                    int* __restrict__ offsets,
                                                    int* __restrict__ cursor, int N)
{
    __shared__ int part[1024];
    int t = threadIdx.x;
    int per = (N + 1023) / 1024;
    int beg = t * per;
    int end = beg + per; if (end > N) end = N; if (beg > N) beg = N;
    int s = 0;
    for (int i = beg; i < end; i++) s += counts[i];
    part[t] = s;
    __syncthreads();
    for (int off = 1; off < 1024; off <<= 1) {
        int v = part[t];
        int u = (t >= off) ? part[t - off] : 0;
        __syncthreads();
        part[t] = v + u;
        __syncthreads();
    }
    int run = (t == 0) ? 0 : part[t - 1];
    for (int i = beg; i < end; i++) {
        offsets[i] = run;
        cursor[i]  = run;
        run += counts[i];
    }
    if (t == 1023) offsets[N] = part[1023];
}

__global__ void scatter_kernel(const int* __restrict__ ei, const int* __restrict__ noff,
                               int* __restrict__ cursor, int* __restrict__ edge_ids, int E)
{
    int i = blockIdx.x * blockDim.x + threadIdx.x;
    if (i < E) {
        int tgt = ei[E + i] - noff[0];
        int pos = atomicAdd(&cursor[tgt], 1);
        edge_ids[pos] = i;
    }
}

// ---------------- Gather: out[n] = x[n] + (1/16) * sum_e env_e * wig_e[:, :5] @ h3_e ----
__global__ __launch_bounds__(256) void gather_kernel(
    const float* __restrict__ x, const unsigned short* __restrict__ h3b,
    const float* __restrict__ wig, const float* __restrict__ env,
    const int* __restrict__ offsets, const int* __restrict__ edge_ids,
    float* __restrict__ out, int N)
{
    __shared__ float sw[25 * 8];   // padded wigner rows [j][k], k<5
    __shared__ float sh[640];      // h3 row as fp32 [k][c]
    int n = blockIdx.x;
    int t = threadIdx.x;
    int c = t & 127;
    int half = t >> 7;             // 0: even j, 1: odd j
    int njj = half ? 12 : 13;
    float acc[13];
    for (int i = 0; i < 13; i++) acc[i] = 0.f;

    int beg = offsets[n], end = offsets[n + 1];
    for (int ii = beg; ii < end; ii++) {
        int e = edge_ids[ii];
        const float* wbase = wig + (size_t)e * 475;   // 25 * 19 floats per edge
        if (t < 125) {
            int j = t / 5, k = t % 5;
            sw[j * 8 + k] = wbase[j * 19 + k];        // row stride is M_ALL = 19
        }
        const unsigned* hp = (const unsigned*)(h3b + (size_t)e * 640);
        for (int idx = t; idx < 320; idx += 256) {
            unsigned u = hp[idx];
            sh[2 * idx]     = __uint_as_float(u << 16);
            sh[2 * idx + 1] = __uint_as_float(u & 0xffff0000u);
        }
        float ev = env[e];
        __syncthreads();
        float hv0 = sh[c], hv1 = sh[128 + c], hv2 = sh[256 + c], hv3 = sh[384 + c], hv4 = sh[512 + c];
        for (int jj = 0; jj < njj; jj++) {
            int j = half + jj * 2;
            float4 w4 = *(float4*)&sw[j * 8];
            float we  = sw[j * 8 + 4];
            float d = w4.x * hv0 + w4.y * hv1 + w4.z * hv2 + w4.w * hv3 + we * hv4;
            acc[jj] += ev * d;
        }
        __syncthreads();
    }

    size_t base = (size_t)n * 3200;
    for (int jj = 0; jj < njj; jj++) {
        int j = half + jj * 2;
        out[base + j * 128 + c] = x[base + j * 128 + c] + acc[jj] * 0.0625f;
    }
}

extern "C" void kernel_launch(void* const* d_in, const int* in_sizes, int n_in,
                              void* d_out, int out_size, void* d_ws, size_t ws_size,
                              hipStream_t stream) {
    const float* x          = (const float*)d_in[0];
    const float* x_edge     = (const float*)d_in[1];
    const int*   edge_index = (const int*)d_in[2];
    const float* wigner     = (const float*)d_in[3];
    const float* envel      = (const float*)d_in[4];
    const int*   node_off   = (const int*)d_in[5];
    const float* W1 = (const float*)d_in[6];
    const float* b1 = (const float*)d_in[7];
    const float* g1 = (const float*)d_in[8];
    const float* be1 = (const float*)d_in[9];
    const float* W2 = (const float*)d_in[10];
    const float* b2 = (const float*)d_in[11];
    const float* g2 = (const float*)d_in[12];
    const float* be2 = (const float*)d_in[13];
    const float* W3 = (const float*)d_in[14];
    const float* b3 = (const float*)d_in[15];
    float* out = (float*)d_out;

    int E = in_sizes[1] / 128;    // 100000
    int N = in_sizes[0] / 3200;   // 6250

    // workspace layout
    char* w = (char*)d_ws;
    float* h2 = (float*)w;              w += (size_t)E * 128 * sizeof(float);
    unsigned short* h3b = (unsigned short*)w; w += (size_t)E * 640 * sizeof(unsigned short);
    int* counts   = (int*)w;            w += (size_t)((N + 63) & ~63) * sizeof(int);
    int* offsets  = (int*)w;            w += (size_t)((N + 1 + 63) & ~63) * sizeof(int);
    int* cursor   = (int*)w;            w += (size_t)((N + 63) & ~63) * sizeof(int);
    int* edge_ids = (int*)w;            w += (size_t)E * sizeof(int);

    hipMemsetAsync(counts, 0, (size_t)N * sizeof(int), stream);

    dim3 blk(256);
    mlp12_kernel<<<dim3((E + 63) / 64), blk, 0, stream>>>(
        x_edge, W1, b1, g1, be1, W2, b2, g2, be2, h2, E);

    hist_kernel<<<dim3((E + 255) / 256), blk, 0, stream>>>(edge_index, node_off, counts, E);
    scan_kernel<<<dim3(1), dim3(1024), 0, stream>>>(counts, offsets, cursor, N);
    scatter_kernel<<<dim3((E + 255) / 256), blk, 0, stream>>>(edge_index, node_off, cursor, edge_ids, E);

    gemm3_kernel<<<dim3((E + 63) / 64, 5), blk, 0, stream>>>(h2, W3, b3, h3b, E);

    gather_kernel<<<dim3(N), blk, 0, stream>>>(x, h3b, wigner, envel, offsets, edge_ids, out, N);
}

// Round 3
// 800.052 us; speedup vs baseline: 1.1586x; 1.1586x over previous
//
#include <hip/hip_runtime.h>
#include <hip/hip_bf16.h>

typedef __attribute__((ext_vector_type(8))) short short8;
typedef __attribute__((ext_vector_type(4))) float floatx4;

static __device__ inline unsigned short f2bf(float f) {
    unsigned u = __float_as_uint(f);
    unsigned r = (u + 0x7fffu + ((u >> 16) & 1u)) >> 16;
    return (unsigned short)r;
}

// ---------------- Fused layer1+layer2: h2 = silu(LN(silu(LN(xe@W1+b1))@W2+b2)) ----------
// Outputs h2 as bf16 [E,128] (consumed only by the MFMA gemm3).
__global__ __launch_bounds__(256) void mlp12_kernel(
    const float* __restrict__ xe,
    const float* __restrict__ W1, const float* __restrict__ b1,
    const float* __restrict__ g1, const float* __restrict__ be1,
    const float* __restrict__ W2, const float* __restrict__ b2,
    const float* __restrict__ g2, const float* __restrict__ be2,
    unsigned short* __restrict__ h2b, int E)
{
    __shared__ float As[64 * 132];
    __shared__ float Bs[16 * 128];
    __shared__ float redS[64 * 16];
    __shared__ float redQ[64 * 16];
    __shared__ float mrow[64];
    __shared__ float rrow[64];

    int t  = threadIdx.x;
    int tx = t & 15;        // output-col group (8 cols each)
    int ty = t >> 4;        // row group (4 rows each)
    int e0 = blockIdx.x * 64;

    for (int idx = t; idx < 64 * 32; idx += 256) {
        int row = idx >> 5;
        int c4  = (idx & 31) * 4;
        float4 v = make_float4(0.f, 0.f, 0.f, 0.f);
        if (e0 + row < E) v = *(const float4*)(xe + (size_t)(e0 + row) * 128 + c4);
        *(float4*)&As[row * 132 + c4] = v;
    }

    const float* Wl = W1; const float* bl = b1; const float* gl = g1; const float* bel = be1;
    float acc[4][8];

    for (int layer = 0; layer < 2; layer++) {
        for (int r = 0; r < 4; r++)
            for (int i = 0; i < 8; i++) acc[r][i] = 0.f;

        for (int kk = 0; kk < 128; kk += 16) {
            __syncthreads();
            for (int idx = t; idx < 16 * 32; idx += 256) {
                int row = idx >> 5;
                int c4  = (idx & 31) * 4;
                *(float4*)&Bs[row * 128 + c4] = *(const float4*)(Wl + (size_t)(kk + row) * 128 + c4);
            }
            __syncthreads();
            for (int k = 0; k < 16; k++) {
                float4 bv0 = *(float4*)&Bs[k * 128 + tx * 8];
                float4 bv1 = *(float4*)&Bs[k * 128 + tx * 8 + 4];
                float b[8] = {bv0.x, bv0.y, bv0.z, bv0.w, bv1.x, bv1.y, bv1.z, bv1.w};
                for (int r = 0; r < 4; r++) {
                    float a = As[(ty * 4 + r) * 132 + kk + k];
                    for (int i = 0; i < 8; i++) acc[r][i] += a * b[i];
                }
            }
        }

        float gg[8], bebe[8];
        for (int i = 0; i < 8; i++) {
            float bb = bl[tx * 8 + i];
            gg[i]    = gl[tx * 8 + i];
            bebe[i]  = bel[tx * 8 + i];
            for (int r = 0; r < 4; r++) acc[r][i] += bb;
        }
        for (int r = 0; r < 4; r++) {
            float s = 0.f, q = 0.f;
            for (int i = 0; i < 8; i++) { s += acc[r][i]; q += acc[r][i] * acc[r][i]; }
            redS[(ty * 4 + r) * 16 + tx] = s;
            redQ[(ty * 4 + r) * 16 + tx] = q;
        }
        __syncthreads();
        if (t < 64) {
            float s = 0.f, q = 0.f;
            for (int i = 0; i < 16; i++) { s += redS[t * 16 + i]; q += redQ[t * 16 + i]; }
            float mu  = s * (1.f / 128.f);
            float var = q * (1.f / 128.f) - mu * mu;
            mrow[t] = mu;
            rrow[t] = rsqrtf(var + 1e-6f);
        }
        __syncthreads();
        for (int r = 0; r < 4; r++) {
            int e_loc = ty * 4 + r;
            float mu = mrow[e_loc], rs = rrow[e_loc];
            for (int i = 0; i < 8; i++) {
                float v = (acc[r][i] - mu) * rs * gg[i] + bebe[i];
                acc[r][i] = v / (1.f + __expf(-v));   // silu
            }
        }
        if (layer == 0) {
            for (int r = 0; r < 4; r++) {
                int e_loc = ty * 4 + r;
                for (int i = 0; i < 8; i++) As[e_loc * 132 + tx * 8 + i] = acc[r][i];
            }
            __syncthreads();
            Wl = W2; bl = b2; gl = g2; bel = be2;
        } else {
            for (int r = 0; r < 4; r++) {
                int e = e0 + ty * 4 + r;
                if (e < E) {
                    unsigned p[4];
                    for (int i = 0; i < 4; i++)
                        p[i] = (unsigned)f2bf(acc[r][2 * i]) | ((unsigned)f2bf(acc[r][2 * i + 1]) << 16);
                    *(uint4*)(h2b + (size_t)e * 128 + tx * 8) = make_uint4(p[0], p[1], p[2], p[3]);
                }
            }
        }
    }
}

// ---------------- W3 transpose prep: W3bT[n][k] = bf16(W3[k][n]), [640][128] ------------
__global__ __launch_bounds__(256) void w3t_kernel(const float* __restrict__ W3,
                                                  unsigned short* __restrict__ W3bT)
{
    int idx = blockIdx.x * 256 + threadIdx.x;   // 81920 total
    int n = idx >> 7, k = idx & 127;
    W3bT[idx] = f2bf(W3[(size_t)k * 640 + n]);
}

// ---------------- Layer 3 via MFMA: h3 = h2 @ W3 + b3, stored bf16 [E,640] --------------
// Block tile 64(M)x128(N), K=128. 4 waves in 2x2; wave tile 32x64.
// B fragments live in registers, loaded straight from L2-resident W3bT.
__global__ __launch_bounds__(256) void gemm3_mfma_kernel(
    const unsigned short* __restrict__ h2b, const unsigned short* __restrict__ W3bT,
    const float* __restrict__ b3, unsigned short* __restrict__ h3b, int E)
{
    __shared__ unsigned short As[64 * 136];   // +8 bf16 pad: row stride 68 dwords -> 2-way max

    int t    = threadIdx.x;
    int lane = t & 63;
    int w    = t >> 6;
    int mw   = w & 1, nw = w >> 1;
    int l15  = lane & 15, quad = lane >> 4;
    int e0   = blockIdx.x * 64;
    int n0   = blockIdx.y * 128;

    // stage A tile (64 x 128 bf16) to LDS
    for (int p = 0; p < 4; p++) {
        int idx = p * 256 + t;              // 1024 16B-chunks
        int row = idx >> 4;
        int c16 = idx & 15;
        uint4 v = make_uint4(0, 0, 0, 0);
        if (e0 + row < E) v = *(const uint4*)(h2b + (size_t)(e0 + row) * 128 + c16 * 8);
        *(uint4*)&As[row * 136 + c16 * 8] = v;
    }

    // B fragments: [kstep][nf], each lane: B[k=ks*32+quad*8+j][n=n_base+nf*16+l15]
    short8 bfrag[4][4];
    {
        const unsigned short* bbase = W3bT + (size_t)(n0 + nw * 64) * 128;
        for (int ks = 0; ks < 4; ks++)
            for (int nf = 0; nf < 4; nf++)
                bfrag[ks][nf] = *(const short8*)(bbase + (size_t)(nf * 16 + l15) * 128 + ks * 32 + quad * 8);
    }

    floatx4 acc[2][4];
    for (int mf = 0; mf < 2; mf++)
        for (int nf = 0; nf < 4; nf++)
            acc[mf][nf] = (floatx4){0.f, 0.f, 0.f, 0.f};

    __syncthreads();

    for (int ks = 0; ks < 4; ks++) {
        short8 afrag[2];
        for (int mf = 0; mf < 2; mf++)
            afrag[mf] = *(const short8*)&As[(mw * 32 + mf * 16 + l15) * 136 + ks * 32 + quad * 8];
        for (int mf = 0; mf < 2; mf++)
            for (int nf = 0; nf < 4; nf++)
                acc[mf][nf] = __builtin_amdgcn_mfma_f32_16x16x32_bf16(
                    afrag[mf], bfrag[ks][nf], acc[mf][nf], 0, 0, 0);
    }

    // epilogue: + b3, pack bf16, store. C/D layout: col=lane&15, row=quad*4+reg.
    for (int nf = 0; nf < 4; nf++) {
        int col = n0 + nw * 64 + nf * 16 + l15;
        float bias = b3[col];
        for (int mf = 0; mf < 2; mf++) {
            int mbase = e0 + mw * 32 + mf * 16 + quad * 4;
            for (int r = 0; r < 4; r++) {
                int m = mbase + r;
                if (m < E) h3b[(size_t)m * 640 + col] = f2bf(acc[mf][nf][r] + bias);
            }
        }
    }
}

// ---------------- CSR build ---------------------------------------------------------
__global__ void hist_kernel(const int* __restrict__ ei, const int* __restrict__ noff,
                            int* __restrict__ counts, int E)
{
    int i = blockIdx.x * blockDim.x + threadIdx.x;
    if (i < E) {
        int tgt = ei[E + i] - noff[0];
        atomicAdd(&counts[tgt], 1);
    }
}

__global__ __launch_bounds__(1024) void scan_kernel(const int* __restrict__ counts,
                                                    int* __restrict__ offsets,
                                                    int* __restrict__ cursor, int N)
{
    __shared__ int part[1024];
    int t = threadIdx.x;
    int per = (N + 1023) / 1024;
    int beg = t * per;
    int end = beg + per; if (end > N) end = N; if (beg > N) beg = N;
    int s = 0;
    for (int i = beg; i < end; i++) s += counts[i];
    part[t] = s;
    __syncthreads();
    for (int off = 1; off < 1024; off <<= 1) {
        int v = part[t];
        int u = (t >= off) ? part[t - off] : 0;
        __syncthreads();
        part[t] = v + u;
        __syncthreads();
    }
    int run = (t == 0) ? 0 : part[t - 1];
    for (int i = beg; i < end; i++) {
        offsets[i] = run;
        cursor[i]  = run;
        run += counts[i];
    }
    if (t == 1023) offsets[N] = part[1023];
}

__global__ void scatter_kernel(const int* __restrict__ ei, const int* __restrict__ noff,
                               int* __restrict__ cursor, int* __restrict__ edge_ids, int E)
{
    int i = blockIdx.x * blockDim.x + threadIdx.x;
    if (i < E) {
        int tgt = ei[E + i] - noff[0];
        int pos = atomicAdd(&cursor[tgt], 1);
        edge_ids[pos] = i;
    }
}

// ---------------- Gather: out[n] = x[n] + (1/16) * sum_e env_e * wig_e[:, :5] @ h3_e ----
__global__ __launch_bounds__(256) void gather_kernel(
    const float* __restrict__ x, const unsigned short* __restrict__ h3b,
    const float* __restrict__ wig, const float* __restrict__ env,
    const int* __restrict__ offsets, const int* __restrict__ edge_ids,
    float* __restrict__ out, int N)
{
    __shared__ float sw[25 * 8];   // padded wigner rows [j][k], k<5
    __shared__ float sh[640];      // h3 row as fp32 [k][c]
    int n = blockIdx.x;
    int t = threadIdx.x;
    int c = t & 127;
    int half = t >> 7;             // 0: even j, 1: odd j
    int njj = half ? 12 : 13;
    float acc[13];
    for (int i = 0; i < 13; i++) acc[i] = 0.f;

    int beg = offsets[n], end = offsets[n + 1];
    for (int ii = beg; ii < end; ii++) {
        int e = edge_ids[ii];
        const float* wbase = wig + (size_t)e * 475;   // 25 * 19 floats per edge
        if (t < 125) {
            int j = t / 5, k = t % 5;
            sw[j * 8 + k] = wbase[j * 19 + k];        // row stride is M_ALL = 19
        }
        const unsigned* hp = (const unsigned*)(h3b + (size_t)e * 640);
        for (int idx = t; idx < 320; idx += 256) {
            unsigned u = hp[idx];
            sh[2 * idx]     = __uint_as_float(u << 16);
            sh[2 * idx + 1] = __uint_as_float(u & 0xffff0000u);
        }
        float ev = env[e];
        __syncthreads();
        float hv0 = sh[c], hv1 = sh[128 + c], hv2 = sh[256 + c], hv3 = sh[384 + c], hv4 = sh[512 + c];
        for (int jj = 0; jj < njj; jj++) {
            int j = half + jj * 2;
            float4 w4 = *(float4*)&sw[j * 8];
            float we  = sw[j * 8 + 4];
            float d = w4.x * hv0 + w4.y * hv1 + w4.z * hv2 + w4.w * hv3 + we * hv4;
            acc[jj] += ev * d;
        }
        __syncthreads();
    }

    size_t base = (size_t)n * 3200;
    for (int jj = 0; jj < njj; jj++) {
        int j = half + jj * 2;
        out[base + j * 128 + c] = x[base + j * 128 + c] + acc[jj] * 0.0625f;
    }
}

extern "C" void kernel_launch(void* const* d_in, const int* in_sizes, int n_in,
                              void* d_out, int out_size, void* d_ws, size_t ws_size,
                              hipStream_t stream) {
    const float* x          = (const float*)d_in[0];
    const float* x_edge     = (const float*)d_in[1];
    const int*   edge_index = (const int*)d_in[2];
    const float* wigner     = (const float*)d_in[3];
    const float* envel      = (const float*)d_in[4];
    const int*   node_off   = (const int*)d_in[5];
    const float* W1 = (const float*)d_in[6];
    const float* b1 = (const float*)d_in[7];
    const float* g1 = (const float*)d_in[8];
    const float* be1 = (const float*)d_in[9];
    const float* W2 = (const float*)d_in[10];
    const float* b2 = (const float*)d_in[11];
    const float* g2 = (const float*)d_in[12];
    const float* be2 = (const float*)d_in[13];
    const float* W3 = (const float*)d_in[14];
    const float* b3 = (const float*)d_in[15];
    float* out = (float*)d_out;

    int E = in_sizes[1] / 128;    // 100000
    int N = in_sizes[0] / 3200;   // 6250

    // workspace layout
    char* w = (char*)d_ws;
    unsigned short* h2b  = (unsigned short*)w; w += (size_t)E * 128 * sizeof(unsigned short);
    unsigned short* h3b  = (unsigned short*)w; w += (size_t)E * 640 * sizeof(unsigned short);
    unsigned short* W3bT = (unsigned short*)w; w += (size_t)640 * 128 * sizeof(unsigned short);
    int* counts   = (int*)w;            w += (size_t)((N + 63) & ~63) * sizeof(int);
    int* offsets  = (int*)w;            w += (size_t)((N + 1 + 63) & ~63) * sizeof(int);
    int* cursor   = (int*)w;            w += (size_t)((N + 63) & ~63) * sizeof(int);
    int* edge_ids = (int*)w;            w += (size_t)E * sizeof(int);

    hipMemsetAsync(counts, 0, (size_t)N * sizeof(int), stream);

    dim3 blk(256);
    mlp12_kernel<<<dim3((E + 63) / 64), blk, 0, stream>>>(
        x_edge, W1, b1, g1, be1, W2, b2, g2, be2, h2b, E);

    w3t_kernel<<<dim3(320), blk, 0, stream>>>(W3, W3bT);

    hist_kernel<<<dim3((E + 255) / 256), blk, 0, stream>>>(edge_index, node_off, counts, E);
    scan_kernel<<<dim3(1), dim3(1024), 0, stream>>>(counts, offsets, cursor, N);
    scatter_kernel<<<dim3((E + 255) / 256), blk, 0, stream>>>(edge_index, node_off, cursor, edge_ids, E);

    gemm3_mfma_kernel<<<dim3((E + 63) / 64, 5), blk, 0, stream>>>(h2b, W3bT, b3, h3b, E);

    gather_kernel<<<dim3(N), blk, 0, stream>>>(x, h3b, wigner, envel, offsets, edge_ids, out, N);
}